// Round 9
// baseline (199.843 us; speedup 1.0000x reference)
//
#include <hip/hip_runtime.h>
#include <cstdint>
#include <cstddef>

// ---------- types ----------
typedef __bf16 bf16;
typedef bf16  bf16x4  __attribute__((ext_vector_type(4)));
typedef bf16  bf16x8  __attribute__((ext_vector_type(8)));
typedef float floatx4 __attribute__((ext_vector_type(4)));

// Problem constants (reference: B=2, S=2048, D=1024, H=16, Dh=64)
#define BATCH 2
#define SEQ   2048
#define DIM   1024
#define NH    16
#define DH    64
#define D3    3072
#define MROWS 4096   // BATCH*SEQ

// async global->LDS, 16B per lane; LDS dest must be wave-uniform base + lane*16
__device__ __forceinline__ void gld16(void* lds, const void* gptr) {
  __builtin_amdgcn_global_load_lds(
      (const __attribute__((address_space(1))) unsigned int*)gptr,
      (__attribute__((address_space(3))) unsigned int*)lds, 16, 0, 0);
}

// ---------- kernel 1: merged prep ----------
// blocks [0,4096): x fp32 -> bf16        (1M float4)
// blocks [4096,7168): W_in  [1024][3072] -> W_in^T  bf16 (32x32 tiles)
// blocks [7168,8192): W_out [1024][1024] -> W_out^T bf16 (32x32 tiles)
__global__ __launch_bounds__(256) void k_prep(const float4* __restrict__ x,
                                              bf16* __restrict__ xb,
                                              const float* __restrict__ Wi,
                                              bf16* __restrict__ wti,
                                              const float* __restrict__ Wo,
                                              bf16* __restrict__ wto) {
  __shared__ float tile[32][33];
  const int bid = blockIdx.x;
  if (bid < 4096) {
    int i = bid * 256 + threadIdx.x;
    float4 v = x[i];
    bf16x4 o;
    o.x = (bf16)v.x; o.y = (bf16)v.y; o.z = (bf16)v.z; o.w = (bf16)v.w;
    *(bf16x4*)(xb + (size_t)i * 4) = o;
    return;
  }
  const float* W; bf16* Wt; int N, id;
  if (bid < 7168) { W = Wi; Wt = wti; N = 3072; id = bid - 4096; }
  else            { W = Wo; Wt = wto; N = 1024; id = bid - 7168; }
  const int nb = N / 32;
  int n0 = (id % nb) * 32, k0 = (id / nb) * 32;
  int tx = threadIdx.x & 31, ty = threadIdx.x >> 5;   // ty in [0,8)
#pragma unroll
  for (int i = 0; i < 4; i++)
    tile[ty + i * 8][tx] = W[(size_t)(k0 + ty + i * 8) * N + n0 + tx];
  __syncthreads();
#pragma unroll
  for (int i = 0; i < 4; i++)
    Wt[(size_t)(n0 + ty + i * 8) * 1024 + k0 + tx] = (bf16)tile[tx][ty + i * 8];
}

// ---------- kernel 2: GEMM  C = A[M][K] * Bt[N][K]^T  (dbuf, 2D grid, NT stores) ----------
// 128xBN tile, BK=32, 4 waves. XOR chunk swizzle -> conflict-free fragment reads.
// Double-buffered staging: stage(kt+1) before compute(kt), one barrier/iter.
// 2D grid, x = N-major: consecutively-dispatched blocks share the A-tile (temporal
// L2 coalescing — R8 showed destroying this costs ~30%). Epilogue uses
// NON-TEMPORAL stores so the ~25 MB output stream doesn't evict the 14 MB of
// inputs from L2/L3 (R7/R8 FETCH = 2.5x ideal).
// MODE 0: plain C[M][N]. MODE 1: qkv-split epilogue (qk stride 2048 / vt transposed).
template <typename OutT, int MODE, int BN>
__global__ __launch_bounds__(256) void k_gemm_bt(const bf16* __restrict__ A,
                                                 const bf16* __restrict__ Bt,
                                                 OutT* __restrict__ C,
                                                 bf16* __restrict__ qk,
                                                 bf16* __restrict__ vt,
                                                 int M, int N, int K) {
  __shared__ __align__(16) bf16 As[2][128 * 32];   // 16 KB
  __shared__ __align__(16) bf16 Bs[2][BN * 32];    // 16 KB (BN=128) / 8 KB (BN=64)
  const int t = threadIdx.x, l = t & 63, w = t >> 6;
  const int q = l >> 4, mm = l & 15;
  const int m0 = blockIdx.y * 128, n0 = blockIdx.x * BN;
  constexpr int MT = (BN == 128) ? 4 : 2;          // m-subtiles per wave
  const int mo = (BN == 128) ? ((w >> 1) * 64) : (w * 32);
  const int no = (BN == 128) ? ((w & 1) * 64) : 0;
  const int sw = (mm >> 1) & 3;                    // fragment-read swizzle

  auto stage = [&](int kt) {
    const int bp = kt & 1;
#pragma unroll
    for (int i = 0; i < 2; i++) {
      int c = t + i * 256;                 // 512 A-chunks of 16B
      int row = c >> 2, pos = c & 3;
      int gs = pos ^ ((row >> 1) & 3);     // source chunk for this LDS slot
      gld16((char*)As[bp] + (size_t)c * 16, A + (size_t)(m0 + row) * K + kt * 32 + gs * 8);
    }
#pragma unroll
    for (int i = 0; i < BN / 64; i++) {    // BN*4 B-chunks
      int c = t + i * 256;
      int row = c >> 2, pos = c & 3;
      int gs = pos ^ ((row >> 1) & 3);
      gld16((char*)Bs[bp] + (size_t)c * 16, Bt + (size_t)(n0 + row) * K + kt * 32 + gs * 8);
    }
  };

  floatx4 acc[MT][4] = {};
  const int nk = K >> 5;

  stage(0);
  __syncthreads();

  for (int kt = 0; kt < nk; kt++) {
    if (kt + 1 < nk) stage(kt + 1);        // in flight during this iter's compute
    const bf16* Ab = As[kt & 1];
    const bf16* Bb = Bs[kt & 1];
    bf16x8 af[MT], bfr[4];
#pragma unroll
    for (int mt = 0; mt < MT; mt++)
      af[mt] = *(const bf16x8*)(Ab + (size_t)(mo + mt * 16 + mm) * 32 + (q ^ sw) * 8);
#pragma unroll
    for (int nt = 0; nt < 4; nt++)
      bfr[nt] = *(const bf16x8*)(Bb + (size_t)(no + nt * 16 + mm) * 32 + (q ^ sw) * 8);
#pragma unroll
    for (int mt = 0; mt < MT; mt++)
#pragma unroll
      for (int nt = 0; nt < 4; nt++)
        acc[mt][nt] = __builtin_amdgcn_mfma_f32_16x16x32_bf16(af[mt], bfr[nt],
                                                              acc[mt][nt], 0, 0, 0);
    if (kt + 1 < nk) __syncthreads();      // drains stage(kt+1); guards buf reuse
  }
  // epilogue: C/D layout col=lane&15, row=(lane>>4)*4+reg. Non-temporal stores.
#pragma unroll
  for (int mt = 0; mt < MT; mt++)
#pragma unroll
    for (int nt = 0; nt < 4; nt++)
#pragma unroll
      for (int r = 0; r < 4; r++) {
        int row = m0 + mo + mt * 16 + q * 4 + r;
        int col = n0 + no + nt * 16 + mm;
        if (MODE == 0) {
          __builtin_nontemporal_store((OutT)acc[mt][nt][r], C + (size_t)row * N + col);
        } else {
          if (col < 2048) {
            __builtin_nontemporal_store((bf16)acc[mt][nt][r], qk + (size_t)row * 2048 + col);
          } else {
            int d = col - 2048;                  // 0..1023
            int hh = d >> 6, dh = d & 63;
            int bb = row >> 11, s = row & 2047;
            __builtin_nontemporal_store((bf16)acc[mt][nt][r],
                vt + ((size_t)(bb * 16 + hh) * 64 + dh) * SEQ + s);
          }
        }
      }
}

// ---------- kernel 3: causal flash attention (64-row Q tile, dbuf K/V, fixed-max) ----------
// 1024 blocks = (b,h) x 32 q-tiles, dispatched qt-DESCENDING (greedy LPT). 4 waves;
// wave w owns q rows w*16..w*16+15. S^T = mfma(K,Q): lane owns q-row = lane&15.
// Fixed softmax max M=24 (log2 units; true scores bounded ~12) -> no max-reduce,
// no alpha, no O-rescale; scale cancels in O = sum(pV)/sum(p). LDS 40960 B -> 4 blocks/CU.
__global__ __launch_bounds__(256, 4) void k_attn(const bf16* __restrict__ qk,
                                                 const bf16* __restrict__ vt,
                                                 bf16* __restrict__ out) {
  const int bx = blockIdx.x;
  const int qt = 31 - (bx >> 5);          // descending: LPT order
  const int bh = bx & 31;
  const int b = bh >> 4, h = bh & 15;
  const int t = threadIdx.x, l = t & 63, w = t >> 6;
  const int q4 = l >> 4, mm = l & 15;
  const int sw = (mm >> 1) & 3;

  // LDS: union{ Qs[2][64][32] 8192 (dead after qf load) ; Ps[4w][16][40] 5120 }
  //      Ks: 2 x [2][64][32] (16384) ; Vs: 2 x [64][64] (16384)  == 40960 total
  __shared__ __align__(16) char lds[8192 + 16384 + 16384];
  bf16* Qs = (bf16*)lds;
  bf16* Ps = (bf16*)lds;                  // per-wave +w*640 elems, row stride 40
  bf16* Ks = (bf16*)(lds + 8192);         // buf bp at +bp*4096 elems
  bf16* Vs = (bf16*)(lds + 8192 + 16384);

  const size_t qkbase = (size_t)b * SEQ * 2048;
  const size_t vtbase = (size_t)bh * 64 * SEQ;

  // stage K (2x gld16, GEMM-style swizzle) + V^T (2x gld16, 8-chunk swizzle) into buf kt&1
  auto stage = [&](int kt) {
    const int bp = kt & 1;
#pragma unroll
    for (int i = 0; i < 2; i++) {
      int row = t >> 2, pos = t & 3;
      int g = pos ^ ((row >> 1) & 3);
      gld16((char*)(Ks + bp * 4096) + ((size_t)t + i * 256) * 16,
            qk + qkbase + (size_t)(kt * 64 + row) * 2048 + 1024 + h * 64 + i * 32 + g * 8);
    }
#pragma unroll
    for (int i = 0; i < 2; i++) {
      int c = t + i * 256;               // 512 chunks: row d = c>>3, slot cc = c&7
      int vr = c >> 3, vc = c & 7;
      int src = vc ^ (vr & 7);
      gld16((char*)(Vs + bp * 4096) + (size_t)c * 16,
            vt + vtbase + (size_t)vr * SEQ + kt * 64 + src * 8);
    }
  };

  { // stage Q tile once: 64 rows x 64 cols -> [ks][64][32] (unswizzled; read once)
    int row = t >> 2, col = (t & 3) * 8;
#pragma unroll
    for (int i = 0; i < 2; i++)
      gld16((char*)Qs + ((size_t)t + i * 256) * 16,
            qk + qkbase + (size_t)(qt * 64 + row) * 2048 + h * 64 + i * 32 + col);
  }
  stage(0);
  __syncthreads();                        // Q + stage(0) landed
  bf16x8 qf[2];
#pragma unroll
  for (int ks = 0; ks < 2; ks++) {
    qf[ks] = *(const bf16x8*)(Qs + (size_t)(ks * 64 + w * 16 + mm) * 32 + q4 * 8);
#pragma unroll
    for (int j = 0; j < 8; j++)           // 1/sqrt(64) * log2(e): exp2-domain softmax
      qf[ks][j] = (bf16)((float)qf[ks][j] * 0.18033688f);
  }
  __syncthreads();                        // all waves read Q before Ps overwrites it

  float l_i = 0.f;
  floatx4 oaccT[4] = {};                  // O^T: d = nt*16+q4*4+r, q-col = mm
  const int qloc = w * 16 + mm;           // lane's q row within tile
  const float FM = 24.0f;                 // fixed log2-domain max bound

  bf16* Pw = Ps + (size_t)w * 640;        // this wave's P region [16][40]

  for (int kt = 0; kt <= qt; kt++) {
    if (kt < qt) stage(kt + 1);           // in flight during this iter's compute
    const bf16* Kb = Ks + (kt & 1) * 4096;
    const bf16* Vb = Vs + (kt & 1) * 4096;

    // S^T tile: 64 k rows x 16 q cols per wave: mfma(A=K, B=Q)
    floatx4 sacc[4] = {};
#pragma unroll
    for (int ks = 0; ks < 2; ks++)
#pragma unroll
      for (int ct = 0; ct < 4; ct++) {
        bf16x8 kf = *(const bf16x8*)(Kb + (size_t)(ks * 64 + ct * 16 + mm) * 32 + (q4 ^ sw) * 8);
        sacc[ct] = __builtin_amdgcn_mfma_f32_16x16x32_bf16(kf, qf[ks], sacc[ct], 0, 0, 0);
      }

    // fixed-max softmax (log2 units): p = exp2(s - FM); mask -> 0 on diagonal tile
    bf16x4 pk[4];
    float rsum = 0.f;
    if (kt == qt) {
#pragma unroll
      for (int ct = 0; ct < 4; ct++)
#pragma unroll
        for (int r = 0; r < 4; r++) {
          float e = (ct * 16 + q4 * 4 + r > qloc)
                        ? 0.f : __builtin_amdgcn_exp2f(sacc[ct][r] - FM);
          pk[ct][r] = (bf16)e;
          rsum += e;
        }
    } else {
#pragma unroll
      for (int ct = 0; ct < 4; ct++)
#pragma unroll
        for (int r = 0; r < 4; r++) {
          float e = __builtin_amdgcn_exp2f(sacc[ct][r] - FM);
          pk[ct][r] = (bf16)e;
          rsum += e;
        }
    }
    rsum += __shfl_xor(rsum, 16, 64);
    rsum += __shfl_xor(rsum, 32, 64);
    l_i += rsum;

    // P^T -> B-operand layout via half-width LDS buffer (two 32-col halves)
#pragma unroll
    for (int ks = 0; ks < 2; ks++) {
      *(bf16x4*)(Pw + (size_t)mm * 40 + q4 * 4)      = pk[ks * 2 + 0];
      *(bf16x4*)(Pw + (size_t)mm * 40 + 16 + q4 * 4) = pk[ks * 2 + 1];
      bf16x8 pf = *(const bf16x8*)(Pw + (size_t)mm * 40 + q4 * 8);
#pragma unroll
      for (int nt = 0; nt < 4; nt++) {
        int chunk = (ks * 4 + q4) ^ (mm & 7);    // undo staging swizzle
        bf16x8 vf = *(const bf16x8*)(Vb + (size_t)(nt * 16 + mm) * 64 + chunk * 8);
        oaccT[nt] = __builtin_amdgcn_mfma_f32_16x16x32_bf16(vf, pf, oaccT[nt], 0, 0, 0);
      }
    }

    if (kt < qt) __syncthreads();          // drains stage(kt+1); guards bufs
  }

  // epilogue: lane owns one q row; normalize and store 4x bf16x4
  float inv = 1.0f / l_i;
  int qrow = qt * 64 + qloc;
  bf16* orow = out + ((size_t)b * SEQ + qrow) * DIM + h * 64;
#pragma unroll
  for (int nt = 0; nt < 4; nt++) {
    bf16x4 o4;
#pragma unroll
    for (int r = 0; r < 4; r++) o4[r] = (bf16)(oaccT[nt][r] * inv);
    *(bf16x4*)(orow + nt * 16 + q4 * 4) = o4;
  }
}

// ---------- launch ----------
extern "C" void kernel_launch(void* const* d_in, const int* in_sizes, int n_in,
                              void* d_out, int out_size, void* d_ws, size_t ws_size,
                              hipStream_t stream) {
  const float* x     = (const float*)d_in[0];   // [2,2048,1024]
  const float* W_in  = (const float*)d_in[1];   // [1024,3072]
  const float* W_out = (const float*)d_in[2];   // [1024,1024]
  float* out = (float*)d_out;                   // [2,2048,1024]

  char* ws = (char*)d_ws;
  bf16* xb   = (bf16*)(ws);                       //  8 MB: x bf16 [4096][1024] (reused: attn out)
  bf16* wti  = (bf16*)(ws + 8388608);             //  6 MB: W_in^T  [3072][1024]
  bf16* wto  = (bf16*)(ws + 14680064);            //  2 MB: W_out^T [1024][1024]
  bf16* qkb  = (bf16*)(ws + 16777216);            // 16 MB: QK bf16 [4096][2048]
  bf16* vtb  = (bf16*)(ws + 33554432);            //  8 MB: V^T bf16 [32*64][2048]
  bf16* attn = xb;                                //  reuse: xb dead after GEMM1

  k_prep<<<8192, 256, 0, stream>>>((const float4*)x, xb, W_in, wti, W_out, wto);
  // GEMM1: M=4096 N=3072 K=1024; 2D grid, x-major shares A-tiles temporally.
  k_gemm_bt<bf16, 1, 128><<<dim3(24, 32), 256, 0, stream>>>(xb, wti, nullptr, qkb, vtb,
                                                            MROWS, D3, DIM);
  k_attn<<<1024, 256, 0, stream>>>(qkb, vtb, attn);
  // GEMM2: M=4096 N=1024 K=1024; 128x64 tiles -> 512 blocks (2/CU).
  k_gemm_bt<float, 0, 64><<<dim3(16, 32), 256, 0, stream>>>(attn, wto, out, nullptr, nullptr,
                                                            MROWS, DIM, DIM);
}

// Round 10
// 175.077 us; speedup vs baseline: 1.1415x; 1.1415x over previous
//
#include <hip/hip_runtime.h>
#include <cstdint>
#include <cstddef>

// ---------- types ----------
typedef __bf16 bf16;
typedef bf16  bf16x4  __attribute__((ext_vector_type(4)));
typedef bf16  bf16x8  __attribute__((ext_vector_type(8)));
typedef float floatx4 __attribute__((ext_vector_type(4)));

// Problem constants (reference: B=2, S=2048, D=1024, H=16, Dh=64)
#define BATCH 2
#define SEQ   2048
#define DIM   1024
#define NH    16
#define DH    64
#define D3    3072
#define MROWS 4096   // BATCH*SEQ

// async global->LDS, 16B per lane; LDS dest must be wave-uniform base + lane*16
__device__ __forceinline__ void gld16(void* lds, const void* gptr) {
  __builtin_amdgcn_global_load_lds(
      (const __attribute__((address_space(1))) unsigned int*)gptr,
      (__attribute__((address_space(3))) unsigned int*)lds, 16, 0, 0);
}

// ---------- kernel 1: merged prep ----------
// blocks [0,4096): x fp32 -> bf16        (1M float4)
// blocks [4096,7168): W_in  [1024][3072] -> W_in^T  bf16 (32x32 tiles)
// blocks [7168,8192): W_out [1024][1024] -> W_out^T bf16 (32x32 tiles)
__global__ __launch_bounds__(256) void k_prep(const float4* __restrict__ x,
                                              bf16* __restrict__ xb,
                                              const float* __restrict__ Wi,
                                              bf16* __restrict__ wti,
                                              const float* __restrict__ Wo,
                                              bf16* __restrict__ wto) {
  __shared__ float tile[32][33];
  const int bid = blockIdx.x;
  if (bid < 4096) {
    int i = bid * 256 + threadIdx.x;
    float4 v = x[i];
    bf16x4 o;
    o.x = (bf16)v.x; o.y = (bf16)v.y; o.z = (bf16)v.z; o.w = (bf16)v.w;
    *(bf16x4*)(xb + (size_t)i * 4) = o;
    return;
  }
  const float* W; bf16* Wt; int N, id;
  if (bid < 7168) { W = Wi; Wt = wti; N = 3072; id = bid - 4096; }
  else            { W = Wo; Wt = wto; N = 1024; id = bid - 7168; }
  const int nb = N / 32;
  int n0 = (id % nb) * 32, k0 = (id / nb) * 32;
  int tx = threadIdx.x & 31, ty = threadIdx.x >> 5;   // ty in [0,8)
#pragma unroll
  for (int i = 0; i < 4; i++)
    tile[ty + i * 8][tx] = W[(size_t)(k0 + ty + i * 8) * N + n0 + tx];
  __syncthreads();
#pragma unroll
  for (int i = 0; i < 4; i++)
    Wt[(size_t)(n0 + ty + i * 8) * 1024 + k0 + tx] = (bf16)tile[tx][ty + i * 8];
}

// ---------- kernel 2: GEMM  C = A[M][K] * Bt[N][K]^T  (3-buf pipelined K-loop) ----------
// 128xBN tile, BK=32, 4 waves. XOR chunk swizzle -> conflict-free fragment reads.
// TRIPLE-buffered staging with raw s_barrier + manual s_waitcnt vmcnt(LN): the
// wait never drains to 0 mid-loop (AITER-style), so each stage(kt) has ~2 compute
// phases in flight. Per-iter: wait(stage(kt) landed, stage(kt+1) still flying);
// barrier (all waves done reading buf[(kt-1)%3]); issue stage(kt+2) into that
// buffer; compute buf[kt%3]. Last iter peeled with vmcnt(0).
// 2D grid, x = N-major (consecutive blocks share the A-tile in L2 — R8 lesson).
// MODE 0: plain C[M][N]. MODE 1: qkv-split epilogue (qk stride 2048 / vt transposed).
template <typename OutT, int MODE, int BN>
__global__ __launch_bounds__(256) void k_gemm_bt(const bf16* __restrict__ A,
                                                 const bf16* __restrict__ Bt,
                                                 OutT* __restrict__ C,
                                                 bf16* __restrict__ qk,
                                                 bf16* __restrict__ vt,
                                                 int M, int N, int K) {
  constexpr int LN = 2 + BN / 64;                  // gld16 per thread per stage
  __shared__ __align__(16) bf16 As[3][128 * 32];   // 24 KB
  __shared__ __align__(16) bf16 Bs[3][BN * 32];    // 24 KB (BN=128) / 12 KB (BN=64)
  const int t = threadIdx.x, l = t & 63, w = t >> 6;
  const int q = l >> 4, mm = l & 15;
  const int m0 = blockIdx.y * 128, n0 = blockIdx.x * BN;
  constexpr int MT = (BN == 128) ? 4 : 2;          // m-subtiles per wave
  const int mo = (BN == 128) ? ((w >> 1) * 64) : (w * 32);
  const int no = (BN == 128) ? ((w & 1) * 64) : 0;
  const int sw = (mm >> 1) & 3;                    // fragment-read swizzle

  auto stage = [&](int kt) {
    const int bp = kt % 3;
#pragma unroll
    for (int i = 0; i < 2; i++) {
      int c = t + i * 256;                 // 512 A-chunks of 16B
      int row = c >> 2, pos = c & 3;
      int gs = pos ^ ((row >> 1) & 3);     // source chunk for this LDS slot
      gld16((char*)As[bp] + (size_t)c * 16, A + (size_t)(m0 + row) * K + kt * 32 + gs * 8);
    }
#pragma unroll
    for (int i = 0; i < BN / 64; i++) {    // BN*4 B-chunks
      int c = t + i * 256;
      int row = c >> 2, pos = c & 3;
      int gs = pos ^ ((row >> 1) & 3);
      gld16((char*)Bs[bp] + (size_t)c * 16, Bt + (size_t)(n0 + row) * K + kt * 32 + gs * 8);
    }
  };

  floatx4 acc[MT][4] = {};
  const int nk = K >> 5;

  stage(0);
  stage(1);                                // 2*LN loads outstanding

  for (int kt = 0; kt < nk; kt++) {
    // stage(kt) landed (mine); join all waves. Never vmcnt(0) until the tail.
    if (kt + 1 < nk)
      asm volatile("s_waitcnt vmcnt(%0)\n\ts_barrier" :: "n"(LN) : "memory");
    else
      asm volatile("s_waitcnt vmcnt(0)\n\ts_barrier" ::: "memory");
    if (kt + 2 < nk) stage(kt + 2);        // overwrites buf[(kt-1)%3]; safe post-barrier

    const bf16* Ab = As[kt % 3];
    const bf16* Bb = Bs[kt % 3];
    bf16x8 af[MT], bfr[4];
#pragma unroll
    for (int mt = 0; mt < MT; mt++)
      af[mt] = *(const bf16x8*)(Ab + (size_t)(mo + mt * 16 + mm) * 32 + (q ^ sw) * 8);
#pragma unroll
    for (int nt = 0; nt < 4; nt++)
      bfr[nt] = *(const bf16x8*)(Bb + (size_t)(no + nt * 16 + mm) * 32 + (q ^ sw) * 8);
#pragma unroll
    for (int mt = 0; mt < MT; mt++)
#pragma unroll
      for (int nt = 0; nt < 4; nt++)
        acc[mt][nt] = __builtin_amdgcn_mfma_f32_16x16x32_bf16(af[mt], bfr[nt],
                                                              acc[mt][nt], 0, 0, 0);
  }
  // epilogue: C/D layout col=lane&15, row=(lane>>4)*4+reg (plain stores — R9: NT = 3x write amp)
#pragma unroll
  for (int mt = 0; mt < MT; mt++)
#pragma unroll
    for (int nt = 0; nt < 4; nt++)
#pragma unroll
      for (int r = 0; r < 4; r++) {
        int row = m0 + mo + mt * 16 + q * 4 + r;
        int col = n0 + no + nt * 16 + mm;
        if (MODE == 0) {
          C[(size_t)row * N + col] = (OutT)acc[mt][nt][r];
        } else {
          if (col < 2048) {
            qk[(size_t)row * 2048 + col] = (bf16)acc[mt][nt][r];
          } else {
            int d = col - 2048;                  // 0..1023
            int hh = d >> 6, dh = d & 63;
            int bb = row >> 11, s = row & 2047;
            vt[((size_t)(bb * 16 + hh) * 64 + dh) * SEQ + s] = (bf16)acc[mt][nt][r];
          }
        }
      }
}

// ---------- kernel 3: causal flash attention (64-row Q tile, dbuf K/V, fixed-max) ----------
// 1024 blocks = (b,h) x 32 q-tiles, dispatched qt-DESCENDING (greedy LPT). 4 waves;
// wave w owns q rows w*16..w*16+15. S^T = mfma(K,Q): lane owns q-row = lane&15.
// Fixed softmax max M=24 (log2 units; true scores bounded ~12) -> no max-reduce,
// no alpha, no O-rescale; scale cancels in O = sum(pV)/sum(p). LDS 40960 B -> 4 blocks/CU.
__global__ __launch_bounds__(256, 4) void k_attn(const bf16* __restrict__ qk,
                                                 const bf16* __restrict__ vt,
                                                 bf16* __restrict__ out) {
  const int bx = blockIdx.x;
  const int qt = 31 - (bx >> 5);          // descending: LPT order
  const int bh = bx & 31;
  const int b = bh >> 4, h = bh & 15;
  const int t = threadIdx.x, l = t & 63, w = t >> 6;
  const int q4 = l >> 4, mm = l & 15;
  const int sw = (mm >> 1) & 3;

  // LDS: union{ Qs[2][64][32] 8192 (dead after qf load) ; Ps[4w][16][40] 5120 }
  //      Ks: 2 x [2][64][32] (16384) ; Vs: 2 x [64][64] (16384)  == 40960 total
  __shared__ __align__(16) char lds[8192 + 16384 + 16384];
  bf16* Qs = (bf16*)lds;
  bf16* Ps = (bf16*)lds;                  // per-wave +w*640 elems, row stride 40
  bf16* Ks = (bf16*)(lds + 8192);         // buf bp at +bp*4096 elems
  bf16* Vs = (bf16*)(lds + 8192 + 16384);

  const size_t qkbase = (size_t)b * SEQ * 2048;
  const size_t vtbase = (size_t)bh * 64 * SEQ;

  // stage K (2x gld16, GEMM-style swizzle) + V^T (2x gld16, 8-chunk swizzle) into buf kt&1
  auto stage = [&](int kt) {
    const int bp = kt & 1;
#pragma unroll
    for (int i = 0; i < 2; i++) {
      int row = t >> 2, pos = t & 3;
      int g = pos ^ ((row >> 1) & 3);
      gld16((char*)(Ks + bp * 4096) + ((size_t)t + i * 256) * 16,
            qk + qkbase + (size_t)(kt * 64 + row) * 2048 + 1024 + h * 64 + i * 32 + g * 8);
    }
#pragma unroll
    for (int i = 0; i < 2; i++) {
      int c = t + i * 256;               // 512 chunks: row d = c>>3, slot cc = c&7
      int vr = c >> 3, vc = c & 7;
      int src = vc ^ (vr & 7);
      gld16((char*)(Vs + bp * 4096) + (size_t)c * 16,
            vt + vtbase + (size_t)vr * SEQ + kt * 64 + src * 8);
    }
  };

  { // stage Q tile once: 64 rows x 64 cols -> [ks][64][32] (unswizzled; read once)
    int row = t >> 2, col = (t & 3) * 8;
#pragma unroll
    for (int i = 0; i < 2; i++)
      gld16((char*)Qs + ((size_t)t + i * 256) * 16,
            qk + qkbase + (size_t)(qt * 64 + row) * 2048 + h * 64 + i * 32 + col);
  }
  stage(0);
  __syncthreads();                        // Q + stage(0) landed
  bf16x8 qf[2];
#pragma unroll
  for (int ks = 0; ks < 2; ks++) {
    qf[ks] = *(const bf16x8*)(Qs + (size_t)(ks * 64 + w * 16 + mm) * 32 + q4 * 8);
#pragma unroll
    for (int j = 0; j < 8; j++)           // 1/sqrt(64) * log2(e): exp2-domain softmax
      qf[ks][j] = (bf16)((float)qf[ks][j] * 0.18033688f);
  }
  __syncthreads();                        // all waves read Q before Ps overwrites it

  float l_i = 0.f;
  floatx4 oaccT[4] = {};                  // O^T: d = nt*16+q4*4+r, q-col = mm
  const int qloc = w * 16 + mm;           // lane's q row within tile
  const float FM = 24.0f;                 // fixed log2-domain max bound

  bf16* Pw = Ps + (size_t)w * 640;        // this wave's P region [16][40]

  for (int kt = 0; kt <= qt; kt++) {
    if (kt < qt) stage(kt + 1);           // in flight during this iter's compute
    const bf16* Kb = Ks + (kt & 1) * 4096;
    const bf16* Vb = Vs + (kt & 1) * 4096;

    // S^T tile: 64 k rows x 16 q cols per wave: mfma(A=K, B=Q)
    floatx4 sacc[4] = {};
#pragma unroll
    for (int ks = 0; ks < 2; ks++)
#pragma unroll
      for (int ct = 0; ct < 4; ct++) {
        bf16x8 kf = *(const bf16x8*)(Kb + (size_t)(ks * 64 + ct * 16 + mm) * 32 + (q4 ^ sw) * 8);
        sacc[ct] = __builtin_amdgcn_mfma_f32_16x16x32_bf16(kf, qf[ks], sacc[ct], 0, 0, 0);
      }

    // fixed-max softmax (log2 units): p = exp2(s - FM); mask -> 0 on diagonal tile
    bf16x4 pk[4];
    float rsum = 0.f;
    if (kt == qt) {
#pragma unroll
      for (int ct = 0; ct < 4; ct++)
#pragma unroll
        for (int r = 0; r < 4; r++) {
          float e = (ct * 16 + q4 * 4 + r > qloc)
                        ? 0.f : __builtin_amdgcn_exp2f(sacc[ct][r] - FM);
          pk[ct][r] = (bf16)e;
          rsum += e;
        }
    } else {
#pragma unroll
      for (int ct = 0; ct < 4; ct++)
#pragma unroll
        for (int r = 0; r < 4; r++) {
          float e = __builtin_amdgcn_exp2f(sacc[ct][r] - FM);
          pk[ct][r] = (bf16)e;
          rsum += e;
        }
    }
    rsum += __shfl_xor(rsum, 16, 64);
    rsum += __shfl_xor(rsum, 32, 64);
    l_i += rsum;

    // P^T -> B-operand layout via half-width LDS buffer (two 32-col halves)
#pragma unroll
    for (int ks = 0; ks < 2; ks++) {
      *(bf16x4*)(Pw + (size_t)mm * 40 + q4 * 4)      = pk[ks * 2 + 0];
      *(bf16x4*)(Pw + (size_t)mm * 40 + 16 + q4 * 4) = pk[ks * 2 + 1];
      bf16x8 pf = *(const bf16x8*)(Pw + (size_t)mm * 40 + q4 * 8);
#pragma unroll
      for (int nt = 0; nt < 4; nt++) {
        int chunk = (ks * 4 + q4) ^ (mm & 7);    // undo staging swizzle
        bf16x8 vf = *(const bf16x8*)(Vb + (size_t)(nt * 16 + mm) * 64 + chunk * 8);
        oaccT[nt] = __builtin_amdgcn_mfma_f32_16x16x32_bf16(vf, pf, oaccT[nt], 0, 0, 0);
      }
    }

    if (kt < qt) __syncthreads();          // drains stage(kt+1); guards bufs
  }

  // epilogue: lane owns one q row; normalize and store 4x bf16x4
  float inv = 1.0f / l_i;
  int qrow = qt * 64 + qloc;
  bf16* orow = out + ((size_t)b * SEQ + qrow) * DIM + h * 64;
#pragma unroll
  for (int nt = 0; nt < 4; nt++) {
    bf16x4 o4;
#pragma unroll
    for (int r = 0; r < 4; r++) o4[r] = (bf16)(oaccT[nt][r] * inv);
    *(bf16x4*)(orow + nt * 16 + q4 * 4) = o4;
  }
}

// ---------- launch ----------
extern "C" void kernel_launch(void* const* d_in, const int* in_sizes, int n_in,
                              void* d_out, int out_size, void* d_ws, size_t ws_size,
                              hipStream_t stream) {
  const float* x     = (const float*)d_in[0];   // [2,2048,1024]
  const float* W_in  = (const float*)d_in[1];   // [1024,3072]
  const float* W_out = (const float*)d_in[2];   // [1024,1024]
  float* out = (float*)d_out;                   // [2,2048,1024]

  char* ws = (char*)d_ws;
  bf16* xb   = (bf16*)(ws);                       //  8 MB: x bf16 [4096][1024] (reused: attn out)
  bf16* wti  = (bf16*)(ws + 8388608);             //  6 MB: W_in^T  [3072][1024]
  bf16* wto  = (bf16*)(ws + 14680064);            //  2 MB: W_out^T [1024][1024]
  bf16* qkb  = (bf16*)(ws + 16777216);            // 16 MB: QK bf16 [4096][2048]
  bf16* vtb  = (bf16*)(ws + 33554432);            //  8 MB: V^T bf16 [32*64][2048]
  bf16* attn = xb;                                //  reuse: xb dead after GEMM1

  k_prep<<<8192, 256, 0, stream>>>((const float4*)x, xb, W_in, wti, W_out, wto);
  // GEMM1: M=4096 N=3072 K=1024; 2D grid, x-major shares A-tiles temporally.
  k_gemm_bt<bf16, 1, 128><<<dim3(24, 32), 256, 0, stream>>>(xb, wti, nullptr, qkb, vtb,
                                                            MROWS, D3, DIM);
  k_attn<<<1024, 256, 0, stream>>>(qkb, vtb, attn);
  // GEMM2: M=4096 N=1024 K=1024; 128x64 tiles -> 512 blocks (2/CU).
  k_gemm_bt<float, 0, 64><<<dim3(16, 32), 256, 0, stream>>>(attn, wto, out, nullptr, nullptr,
                                                            MROWS, DIM, DIM);
}